// Round 7
// baseline (534.008 us; speedup 1.0000x reference)
//
#include <hip/hip_runtime.h>
#include <hip/hip_bf16.h>

// Problem constants (T=2048, B=32, N=1024, H=8, K=128, K2=16)
#define T_DIM 2048
#define B_DIM 32
#define N_DIM 1024
#define H_DIM 8
#define K_DIM 128
#define Q_DIM 16

typedef __bf16 bf16x8 __attribute__((ext_vector_type(8)));
typedef __bf16 bf16x4 __attribute__((ext_vector_type(4)));
typedef float  f32x4  __attribute__((ext_vector_type(4)));

__device__ inline bf16x8 cvt8(float4 a, float4 b) {
    bf16x8 r;
    r[0] = (__bf16)a.x; r[1] = (__bf16)a.y; r[2] = (__bf16)a.z; r[3] = (__bf16)a.w;
    r[4] = (__bf16)b.x; r[5] = (__bf16)b.y; r[6] = (__bf16)b.z; r[7] = (__bf16)b.w;
    return r;
}

// ---------------------------------------------------------------------------
// K0: f32 -> bf16 convert, 8 elems/thread.
// ---------------------------------------------------------------------------
__global__ __launch_bounds__(256)
void cvt_f32_bf16(const float* __restrict__ s, __bf16* __restrict__ d)
{
    const long i = ((long)blockIdx.x * 256 + threadIdx.x) * 8;
    float4 a = *(const float4*)(s + i);
    float4 b = *(const float4*)(s + i + 4);
    *(bf16x8*)(d + i) = cvt8(a, b);
}

// ---------------------------------------------------------------------------
// K1: 256x256-tile GEMM, operand-swapped MFMA, pipelined LDS reads, fully
// unrolled K-loop (ds_read = per-thread base + 16-bit immediate). Staging
// offset folded into the GLOBAL pointer (offset arg of global_load_lds kept
// 0 — the only ladder-verified usage; R6's nonzero offset scrambled LDS).
// Counted vmcnt(8) (T4); XOR-swizzled LDS (T2); setprio (T5).
// Fused time-mean partials in epilogue; coalesced bf16x4 stores.
// ---------------------------------------------------------------------------
__global__ __launch_bounds__(512, 1)
void gemm_x_8ph(const __bf16* __restrict__ A, const __bf16* __restrict__ Bw,
                const float* __restrict__ bias, __bf16* __restrict__ X,
                float* __restrict__ mpart)
{
    __shared__ __bf16 ldsA[2][16384];   // [slot][256 rows * 64 k]
    __shared__ __bf16 ldsB[2][16384];

    const int tid  = threadIdx.x;
    const int lane = tid & 63;
    const int w    = tid >> 6;     // 0..7
    const int wm   = w >> 2;       // 0..1 -> 128 rows
    const int wn   = w & 3;        // 0..3 -> 64 cols

    const int bid  = blockIdx.x;                    // 1024 blocks, %8==0
    const int wgid = (bid & 7) * 128 + (bid >> 3);  // bijective XCD swizzle
    const int bm   = wgid >> 2;                     // 0..255
    const int bn   = wgid & 3;                      // 0..3
    const long row0 = (long)bm * 256;
    const long col0 = (long)bn * 256;

    // staging: thread covers rows j*64 + w*8 + (lane>>3), j=0..3, per matrix.
    // global col chunk pre-swizzled so linear LDS dest + swizzled read match.
    const int srow = w * 8 + (lane >> 3);
    const int scol = ((lane & 7) ^ (lane >> 3)) * 8;
    const __bf16* Ag = A  + (row0 + srow) * 1024 + scol;
    const __bf16* Bg = Bw + (col0 + srow) * 1024 + scol;
    const int ldst = w * 512;   // LDS dest elem base (+ j*4096), wave-uniform

    const int fr = lane & 15;
    const int g2 = lane >> 4;    // 0..3: 16B chunk within k-half
    const int x7 = lane & 7;     // read-side XOR key

    // 4 per-thread LDS read bases; all reads = base + compile-time immediate.
    const __bf16* aK0 = &ldsA[0][(wm * 128 + fr) * 64] + ((g2    ) ^ x7) * 8;
    const __bf16* aK1 = &ldsA[0][(wm * 128 + fr) * 64] + ((4 + g2) ^ x7) * 8;
    const __bf16* bK0 = &ldsB[0][(wn * 64  + fr) * 64] + ((g2    ) ^ x7) * 8;
    const __bf16* bK1 = &ldsB[0][(wn * 64  + fr) * 64] + ((4 + g2) ^ x7) * 8;

    f32x4 acc[8][4];
    #pragma unroll
    for (int i = 0; i < 8; ++i)
        #pragma unroll
        for (int j = 0; j < 4; ++j)
            acc[i][j] = f32x4{0.f, 0.f, 0.f, 0.f};

    // stage(kt, sl): 8 global_load_lds; K-offset folded into global pointer
    // (compile-time constant with KT), offset arg stays 0 (verified usage).
    #define STAGE(KT, SL)                                                      \
        {                                                                      \
            _Pragma("unroll")                                                  \
            for (int j = 0; j < 4; ++j)                                        \
                __builtin_amdgcn_global_load_lds(                              \
                    (const __attribute__((address_space(1))) void*)(Ag + (long)j * 65536 + (KT) * 64), \
                    (__attribute__((address_space(3))) void*)(&ldsA[SL][j * 4096 + ldst]), \
                    16, 0, 0);                                                 \
            _Pragma("unroll")                                                  \
            for (int j = 0; j < 4; ++j)                                        \
                __builtin_amdgcn_global_load_lds(                              \
                    (const __attribute__((address_space(1))) void*)(Bg + (long)j * 65536 + (KT) * 64), \
                    (__attribute__((address_space(3))) void*)(&ldsB[SL][j * 4096 + ldst]), \
                    16, 0, 0);                                                 \
        }

    STAGE(0, 0);
    STAGE(1, 1);
    asm volatile("s_waitcnt vmcnt(8)" ::: "memory");   // KT0 landed
    __builtin_amdgcn_sched_barrier(0);
    __builtin_amdgcn_s_barrier();

    // loop-carried G1 frags (a0 k0-half, b0 k0-half) for KT0
    bf16x8 a0[4], b0[4];
    #pragma unroll
    for (int mi = 0; mi < 4; ++mi) a0[mi] = *(const bf16x8*)(aK0 + mi * 1024);
    #pragma unroll
    for (int ni = 0; ni < 4; ++ni) b0[ni] = *(const bf16x8*)(bK0 + ni * 1024);

    #pragma unroll
    for (int i = 0; i < 16; ++i) {
        const int so = (i & 1) * 16384;    // compile-time slot elem offset

        bf16x8 a0h[4], b1[4], a1[4], a1h[4];

        // G2 (a0h k1, b1 k1); M1 consumes G1
        #pragma unroll
        for (int mi = 0; mi < 4; ++mi) a0h[mi] = *(const bf16x8*)(aK1 + so + mi * 1024);
        #pragma unroll
        for (int ni = 0; ni < 4; ++ni) b1[ni]  = *(const bf16x8*)(bK1 + so + ni * 1024);

        __builtin_amdgcn_s_setprio(1);
        #pragma unroll
        for (int mi = 0; mi < 4; ++mi)
            #pragma unroll
            for (int ni = 0; ni < 4; ++ni)
                acc[mi][ni] = __builtin_amdgcn_mfma_f32_16x16x32_bf16(b0[ni], a0[mi], acc[mi][ni], 0, 0, 0);
        __builtin_amdgcn_s_setprio(0);

        // G3 (a1 k0, a1h k1); M2 consumes G2
        #pragma unroll
        for (int mi = 0; mi < 4; ++mi) {
            a1[mi]  = *(const bf16x8*)(aK0 + so + (mi + 4) * 1024);
            a1h[mi] = *(const bf16x8*)(aK1 + so + (mi + 4) * 1024);
        }
        __builtin_amdgcn_s_setprio(1);
        #pragma unroll
        for (int mi = 0; mi < 4; ++mi)
            #pragma unroll
            for (int ni = 0; ni < 4; ++ni)
                acc[mi][ni] = __builtin_amdgcn_mfma_f32_16x16x32_bf16(b1[ni], a0h[mi], acc[mi][ni], 0, 0, 0);
        __builtin_amdgcn_s_setprio(0);

        // all reads of slot s drained everywhere -> safe to overwrite
        asm volatile("s_waitcnt lgkmcnt(0)" ::: "memory");
        __builtin_amdgcn_sched_barrier(0);
        __builtin_amdgcn_s_barrier();
        if (i == 0)  STAGE(2, 0);
        if (i == 1)  STAGE(3, 1);
        if (i == 2)  STAGE(4, 0);
        if (i == 3)  STAGE(5, 1);
        if (i == 4)  STAGE(6, 0);
        if (i == 5)  STAGE(7, 1);
        if (i == 6)  STAGE(8, 0);
        if (i == 7)  STAGE(9, 1);
        if (i == 8)  STAGE(10, 0);
        if (i == 9)  STAGE(11, 1);
        if (i == 10) STAGE(12, 0);
        if (i == 11) STAGE(13, 1);
        if (i == 12) STAGE(14, 0);
        if (i == 13) STAGE(15, 1);

        // M3 consumes G3 k0
        __builtin_amdgcn_s_setprio(1);
        #pragma unroll
        for (int mi = 0; mi < 4; ++mi)
            #pragma unroll
            for (int ni = 0; ni < 4; ++ni)
                acc[mi + 4][ni] = __builtin_amdgcn_mfma_f32_16x16x32_bf16(b0[ni], a1[mi], acc[mi + 4][ni], 0, 0, 0);
        __builtin_amdgcn_s_setprio(0);

        // KT i+1 fully landed everywhere, then prefetch next G1 under M4
        if (i < 14)       { asm volatile("s_waitcnt vmcnt(8)" ::: "memory"); }
        else if (i == 14) { asm volatile("s_waitcnt vmcnt(0)" ::: "memory"); }
        __builtin_amdgcn_sched_barrier(0);
        if (i < 15) __builtin_amdgcn_s_barrier();
        if (i < 15) {
            const int sn = ((i + 1) & 1) * 16384;
            #pragma unroll
            for (int mi = 0; mi < 4; ++mi) a0[mi] = *(const bf16x8*)(aK0 + sn + mi * 1024);
            #pragma unroll
            for (int ni = 0; ni < 4; ++ni) b0[ni] = *(const bf16x8*)(bK0 + sn + ni * 1024);
        }

        __builtin_amdgcn_s_setprio(1);
        #pragma unroll
        for (int mi = 0; mi < 4; ++mi)
            #pragma unroll
            for (int ni = 0; ni < 4; ++ni)
                acc[mi + 4][ni] = __builtin_amdgcn_mfma_f32_16x16x32_bf16(b1[ni], a1h[mi], acc[mi + 4][ni], 0, 0, 0);
        __builtin_amdgcn_s_setprio(0);
    }
    #undef STAGE

    // ------------------ epilogue ------------------
    // Transposed D: element (row = wm*128+mi*16+fr, col = wn*64+ni*16+g4*4+j).
    // One bf16x4 store per (mi,ni). Lane-local mean partial over b = fr+16*(mi&1).
    const int g4 = lane >> 4;
    const long colb = col0 + wn * 64 + g4 * 4;

    float4 bias4[4];
    #pragma unroll
    for (int ni = 0; ni < 4; ++ni)
        bias4[ni] = *(const float4*)(bias + colb + ni * 16);

    f32x4 msum[2][4];
    #pragma unroll
    for (int bh = 0; bh < 2; ++bh)
        #pragma unroll
        for (int ni = 0; ni < 4; ++ni)
            msum[bh][ni] = f32x4{0.f, 0.f, 0.f, 0.f};

    #pragma unroll
    for (int mi = 0; mi < 8; ++mi) {
        const long row = row0 + wm * 128 + mi * 16 + fr;
        #pragma unroll
        for (int ni = 0; ni < 4; ++ni) {
            f32x4 xv;
            xv[0] = acc[mi][ni][0] + bias4[ni].x;
            xv[1] = acc[mi][ni][1] + bias4[ni].y;
            xv[2] = acc[mi][ni][2] + bias4[ni].z;
            xv[3] = acc[mi][ni][3] + bias4[ni].w;
            bf16x4 xb;
            xb[0] = (__bf16)xv[0]; xb[1] = (__bf16)xv[1];
            xb[2] = (__bf16)xv[2]; xb[3] = (__bf16)xv[3];
            *(bf16x4*)(X + row * 1024 + colb + ni * 16) = xb;
            msum[mi & 1][ni] += xv;
        }
    }

    // cross-wave (wm) reduce of mean partials through LDS (free after K-loop)
    float* ldsf = (float*)&ldsA[0][0];    // 32 b x 256 n f32 = 32 KB
    __syncthreads();                      // all K-loop LDS traffic done
    if (wm == 1) {
        #pragma unroll
        for (int bh = 0; bh < 2; ++bh)
            #pragma unroll
            for (int ni = 0; ni < 4; ++ni)
                *(f32x4*)(ldsf + (bh * 16 + fr) * 256 + wn * 64 + ni * 16 + g4 * 4) = msum[bh][ni];
    }
    __syncthreads();
    if (wm == 0) {
        #pragma unroll
        for (int bh = 0; bh < 2; ++bh) {
            const int b = bh * 16 + fr;
            #pragma unroll
            for (int ni = 0; ni < 4; ++ni) {
                f32x4 other = *(const f32x4*)(ldsf + b * 256 + wn * 64 + ni * 16 + g4 * 4);
                f32x4 tot = msum[bh][ni] + other;
                *(f32x4*)(mpart + ((long)bm * 32 + b) * 1024 + colb + ni * 16) = tot;
            }
        }
    }
}

// ---------------------------------------------------------------------------
// K3: finalize mean from fused partials, gate2[b,h,q] = tanh(m.Wm[q]+bWm[q]).
// ---------------------------------------------------------------------------
__global__ __launch_bounds__(256)
void gate2_k(const float* __restrict__ mpart, const float* __restrict__ Wm,
             const float* __restrict__ bWm, float* __restrict__ g2)
{
    __shared__ float mrow[1024];
    const int b = blockIdx.x;
    const int j4 = threadIdx.x * 4;
    f32x4 s = f32x4{0.f, 0.f, 0.f, 0.f};
    for (int bm = 0; bm < 256; ++bm)
        s += *(const f32x4*)(mpart + ((long)bm * 32 + b) * 1024 + j4);
    mrow[j4 + 0] = s[0] * (1.0f / 2048.0f);
    mrow[j4 + 1] = s[1] * (1.0f / 2048.0f);
    mrow[j4 + 2] = s[2] * (1.0f / 2048.0f);
    mrow[j4 + 3] = s[3] * (1.0f / 2048.0f);
    __syncthreads();
    if (threadIdx.x < 128) {
        const int h = threadIdx.x >> 4;
        const int q = threadIdx.x & 15;
        float d = bWm[q];
        #pragma unroll 8
        for (int k = 0; k < 128; ++k) d += mrow[h * 128 + k] * Wm[q * 128 + k];
        g2[(b * 8 + h) * 16 + q] = tanhf(d);
    }
}

// ---------------------------------------------------------------------------
// K4: scores. X viewed as (524288 rows = bt*8+h, 128). One wave = 16 rows.
// ---------------------------------------------------------------------------
__global__ __launch_bounds__(256)
void scores_k(const __bf16* __restrict__ X, const float* __restrict__ W,
              const float* __restrict__ bW, const float* __restrict__ g2,
              const float* __restrict__ Wh, const float* __restrict__ bWh,
              float* __restrict__ sbuf)
{
    const int tid   = threadIdx.x;
    const int lane  = tid & 63;
    const int w     = tid >> 6;
    const int gw    = blockIdx.x * 4 + w;
    const int rbase = gw * 16;
    const int q     = lane & 15;
    const int g4    = lane >> 4;

    bf16x8 bfr[4];
    #pragma unroll
    for (int c = 0; c < 4; ++c) {
        const float* wp = W + q * 128 + c * 32 + g4 * 8;
        float4 w0 = *(const float4*)wp;
        float4 w1 = *(const float4*)(wp + 4);
        bfr[c] = cvt8(w0, w1);
    }
    const __bf16* xp = X + (long)(rbase + q) * 128 + g4 * 8;
    bf16x8 afr[4];
    #pragma unroll
    for (int c = 0; c < 4; ++c) afr[c] = *(const bf16x8*)(xp + c * 32);

    f32x4 acc = f32x4{0.f, 0.f, 0.f, 0.f};
    #pragma unroll
    for (int c = 0; c < 4; ++c)
        acc = __builtin_amdgcn_mfma_f32_16x16x32_bf16(afr[c], bfr[c], acc, 0, 0, 0);

    const float whq  = Wh[q];
    const float bWv  = bW[q];
    const float bWhv = *bWh;
    #pragma unroll
    for (int r = 0; r < 4; ++r) {
        const int row = rbase + g4 * 4 + r;
        const int h   = row & 7;
        const int bt  = row >> 3;
        const int b   = bt & 31;
        const int t   = bt >> 5;
        float val = tanhf(acc[r] + bWv) * g2[(b * 8 + h) * 16 + q] * whq;
        val += __shfl_xor(val, 1);
        val += __shfl_xor(val, 2);
        val += __shfl_xor(val, 4);
        val += __shfl_xor(val, 8);
        if (q == 0) sbuf[(b * 8 + h) * 2048 + t] = val + bWhv;
    }
}

// ---------------------------------------------------------------------------
// K5: softmax over t, in place. 256 blocks (b*8+h).
// ---------------------------------------------------------------------------
__global__ __launch_bounds__(256)
void softmax_k(float* __restrict__ s)
{
    __shared__ float red[256];
    const int bh = blockIdx.x;
    const int tid = threadIdx.x;
    float* row = s + bh * 2048;
    float4 v0 = *(const float4*)(row + tid * 8);
    float4 v1 = *(const float4*)(row + tid * 8 + 4);
    float v[8] = {v0.x, v0.y, v0.z, v0.w, v1.x, v1.y, v1.z, v1.w};
    float mx = v[0];
    #pragma unroll
    for (int i = 1; i < 8; ++i) mx = fmaxf(mx, v[i]);
    red[tid] = mx;
    __syncthreads();
    for (int st = 128; st > 0; st >>= 1) {
        if (tid < st) red[tid] = fmaxf(red[tid], red[tid + st]);
        __syncthreads();
    }
    mx = red[0];
    __syncthreads();
    float sum = 0.f;
    #pragma unroll
    for (int i = 0; i < 8; ++i) { v[i] = expf(v[i] - mx); sum += v[i]; }
    red[tid] = sum;
    __syncthreads();
    for (int st = 128; st > 0; st >>= 1) {
        if (tid < st) red[tid] += red[tid + st];
        __syncthreads();
    }
    const float inv = 1.0f / red[0];
    *(float4*)(row + tid * 8)     = make_float4(v[0] * inv, v[1] * inv, v[2] * inv, v[3] * inv);
    *(float4*)(row + tid * 8 + 4) = make_float4(v[4] * inv, v[5] * inv, v[6] * inv, v[7] * inv);
}

// ---------------------------------------------------------------------------
// K6: weighted sum over t, t split 8 ways. 2048 blocks.
// ---------------------------------------------------------------------------
__global__ __launch_bounds__(256)
void wsum_k(const float* __restrict__ a, const __bf16* __restrict__ X,
            float* __restrict__ wpart)
{
    __shared__ float pk[8 * 128];
    const int bx = blockIdx.x;
    const int tc = bx & 7;
    const int bh = bx >> 3;
    const int b  = bh >> 3;
    const int h  = bh & 7;
    const int tid = threadIdx.x;
    const int kq = tid & 31;
    const int tr = tid >> 5;
    const float* ar = a + bh * 2048 + tc * 256;
    float a0 = 0.f, a1 = 0.f, a2 = 0.f, a3 = 0.f;
    #pragma unroll 4
    for (int i = tr; i < 256; i += 8) {
        const int t = tc * 256 + i;
        const float av = ar[i];
        bf16x4 xv = *(const bf16x4*)(X + (long)(t * 32 + b) * 1024 + h * 128 + kq * 4);
        a0 += av * (float)xv[0];
        a1 += av * (float)xv[1];
        a2 += av * (float)xv[2];
        a3 += av * (float)xv[3];
    }
    pk[tr * 128 + kq * 4 + 0] = a0;
    pk[tr * 128 + kq * 4 + 1] = a1;
    pk[tr * 128 + kq * 4 + 2] = a2;
    pk[tr * 128 + kq * 4 + 3] = a3;
    __syncthreads();
    if (tid < 128) {
        float s2 = 0.f;
        #pragma unroll
        for (int r = 0; r < 8; ++r) s2 += pk[r * 128 + tid];
        wpart[(long)bx * 128 + tid] = s2;
    }
}

// K7: reduce the 8 t-chunks.
__global__ __launch_bounds__(256)
void wsum_fin(const float* __restrict__ wpart, float* __restrict__ out)
{
    const int idx = blockIdx.x * 256 + threadIdx.x;
    const int k  = idx & 127;
    const int bh = idx >> 7;
    const int b  = bh >> 3;
    const int h  = bh & 7;
    float s = 0.f;
    #pragma unroll
    for (int tc = 0; tc < 8; ++tc) s += wpart[(bh * 8 + tc) * 128 + k];
    out[b * 1024 + h * 128 + k] = s;
}

extern "C" void kernel_launch(void* const* d_in, const int* in_sizes, int n_in,
                              void* d_out, int out_size, void* d_ws, size_t ws_size,
                              hipStream_t stream)
{
    const float* hyp = (const float*)d_in[0];
    const float* Wmh = (const float*)d_in[1];
    const float* bmh = (const float*)d_in[2];
    const float* W   = (const float*)d_in[3];
    const float* bW  = (const float*)d_in[4];
    const float* Wm  = (const float*)d_in[5];
    const float* bWm = (const float*)d_in[6];
    const float* Wh  = (const float*)d_in[7];
    const float* bWh = (const float*)d_in[8];
    float* out = (float*)d_out;

    char* ws = (char*)d_ws;
    const size_t SZ_X   = 134217728;   // X bf16 (65536 x 1024)
    const size_t SZ_AB  = 134217728;   // Ab bf16 hyp
    const size_t SZ_BB  = 2097152;     // Bb bf16 Wmh
    const size_t SZ_MP  = 33554432;    // mpart f32 (256 x 32 x 1024)
    const size_t SZ_G2  = 16384;
    const size_t SZ_SB  = 2097152;

    size_t off = 0;
    __bf16* X     = (__bf16*)(ws + off); off += SZ_X;
    __bf16* Ab    = (__bf16*)(ws + off); off += SZ_AB;
    __bf16* Bb    = (__bf16*)(ws + off); off += SZ_BB;
    float*  mpart = (float*) (ws + off); off += SZ_MP;
    float*  g2    = (float*) (ws + off); off += SZ_G2;
    float*  sbuf  = (float*) (ws + off); off += SZ_SB;
    float*  wpart = (float*) (ws + off);

    cvt_f32_bf16<<<32768, 256, 0, stream>>>(hyp, Ab);
    cvt_f32_bf16<<<512,   256, 0, stream>>>(Wmh, Bb);
    gemm_x_8ph<<<1024, 512, 0, stream>>>(Ab, Bb, bmh, X, mpart);
    gate2_k<<<32, 256, 0, stream>>>(mpart, Wm, bWm, g2);
    scores_k<<<8192, 256, 0, stream>>>(X, W, bW, g2, Wh, bWh, sbuf);
    softmax_k<<<256, 256, 0, stream>>>(sbuf);
    wsum_k<<<2048, 256, 0, stream>>>(sbuf, X, wpart);
    wsum_fin<<<128, 256, 0, stream>>>(wpart, out);
}

// Round 8
// 341.863 us; speedup vs baseline: 1.5621x; 1.5621x over previous
//
#include <hip/hip_runtime.h>
#include <hip/hip_bf16.h>

// Problem constants (T=2048, B=32, N=1024, H=8, K=128, K2=16)
#define T_DIM 2048
#define B_DIM 32
#define N_DIM 1024
#define H_DIM 8
#define K_DIM 128
#define Q_DIM 16

typedef __bf16 bf16x8 __attribute__((ext_vector_type(8)));
typedef __bf16 bf16x4 __attribute__((ext_vector_type(4)));
typedef float  f32x4  __attribute__((ext_vector_type(4)));

__device__ inline bf16x8 cvt8(float4 a, float4 b) {
    bf16x8 r;
    r[0] = (__bf16)a.x; r[1] = (__bf16)a.y; r[2] = (__bf16)a.z; r[3] = (__bf16)a.w;
    r[4] = (__bf16)b.x; r[5] = (__bf16)b.y; r[6] = (__bf16)b.z; r[7] = (__bf16)b.w;
    return r;
}

// ---------------------------------------------------------------------------
// K0: f32 -> bf16 convert, 8 elems/thread.
// ---------------------------------------------------------------------------
__global__ __launch_bounds__(256)
void cvt_f32_bf16(const float* __restrict__ s, __bf16* __restrict__ d)
{
    const long i = ((long)blockIdx.x * 256 + threadIdx.x) * 8;
    float4 a = *(const float4*)(s + i);
    float4 b = *(const float4*)(s + i + 4);
    *(bf16x8*)(d + i) = cvt8(a, b);
}

// ---------------------------------------------------------------------------
// K1: 256x256-tile GEMM, operand-swapped MFMA, pipelined LDS reads.
// UNROLL-BY-2 K-loop: slot offsets are compile-time literals (ds_read =
// loop-invariant base + 16-bit immediate, zero VALU), while staging uses
// TWO loop-carried pointers bumped +128 elems/iter (no per-KT address
// explosion -> no spills, unlike the R7 full unroll). R5 schedule invariants:
// G2/G3 reads one MFMA-group ahead; lgkmcnt(0)+barrier before slot overwrite;
// counted vmcnt(8) (never 0 mid-loop); prefetch next G1 under M4.
// XOR-swizzled LDS (T2); setprio (T5). Fused mean partials in epilogue.
// ---------------------------------------------------------------------------
__global__ __launch_bounds__(512, 1)
void gemm_x_8ph(const __bf16* __restrict__ A, const __bf16* __restrict__ Bw,
                const float* __restrict__ bias, __bf16* __restrict__ X,
                float* __restrict__ mpart)
{
    __shared__ __bf16 ldsA[2][16384];   // [slot][256 rows * 64 k]
    __shared__ __bf16 ldsB[2][16384];

    const int tid  = threadIdx.x;
    const int lane = tid & 63;
    const int w    = tid >> 6;     // 0..7
    const int wm   = w >> 2;       // 0..1 -> 128 rows
    const int wn   = w & 3;        // 0..3 -> 64 cols

    const int bid  = blockIdx.x;                    // 1024 blocks, %8==0
    const int wgid = (bid & 7) * 128 + (bid >> 3);  // bijective XCD swizzle
    const int bm   = wgid >> 2;                     // 0..255
    const int bn   = wgid & 3;                      // 0..3
    const long row0 = (long)bm * 256;
    const long col0 = (long)bn * 256;

    // staging: thread covers rows j*64 + w*8 + (lane>>3), j=0..3, per matrix.
    // global col chunk pre-swizzled so linear LDS dest + swizzled read match.
    const int srow = w * 8 + (lane >> 3);
    const int scol = ((lane & 7) ^ (lane >> 3)) * 8;
    const __bf16* Ag = A  + (row0 + srow) * 1024 + scol;
    const __bf16* Bg = Bw + (col0 + srow) * 1024 + scol;
    const int ldst = w * 512;   // LDS dest elem base (+ j*4096), wave-uniform

    const int fr = lane & 15;
    const int g2 = lane >> 4;    // 0..3: 16B chunk within k-half
    const int x7 = lane & 7;     // read-side XOR key

    // 4 per-thread LDS read bases; all reads = base + compile-time immediate.
    const __bf16* aK0 = &ldsA[0][(wm * 128 + fr) * 64] + ((g2    ) ^ x7) * 8;
    const __bf16* aK1 = &ldsA[0][(wm * 128 + fr) * 64] + ((4 + g2) ^ x7) * 8;
    const __bf16* bK0 = &ldsB[0][(wn * 64  + fr) * 64] + ((g2    ) ^ x7) * 8;
    const __bf16* bK1 = &ldsB[0][(wn * 64  + fr) * 64] + ((4 + g2) ^ x7) * 8;

    f32x4 acc[8][4];
    #pragma unroll
    for (int i = 0; i < 8; ++i)
        #pragma unroll
        for (int j = 0; j < 4; ++j)
            acc[i][j] = f32x4{0.f, 0.f, 0.f, 0.f};

    // prologue staging of KT0/KT1 (global addr = Ag/Bg + kt*64 elems)
    #pragma unroll
    for (int j = 0; j < 4; ++j) {
        __builtin_amdgcn_global_load_lds(
            (const __attribute__((address_space(1))) void*)(Ag + (long)j * 65536),
            (__attribute__((address_space(3))) void*)(&ldsA[0][j * 4096 + ldst]), 16, 0, 0);
        __builtin_amdgcn_global_load_lds(
            (const __attribute__((address_space(1))) void*)(Bg + (long)j * 65536),
            (__attribute__((address_space(3))) void*)(&ldsB[0][j * 4096 + ldst]), 16, 0, 0);
    }
    #pragma unroll
    for (int j = 0; j < 4; ++j) {
        __builtin_amdgcn_global_load_lds(
            (const __attribute__((address_space(1))) void*)(Ag + (long)j * 65536 + 64),
            (__attribute__((address_space(3))) void*)(&ldsA[1][j * 4096 + ldst]), 16, 0, 0);
        __builtin_amdgcn_global_load_lds(
            (const __attribute__((address_space(1))) void*)(Bg + (long)j * 65536 + 64),
            (__attribute__((address_space(3))) void*)(&ldsB[1][j * 4096 + ldst]), 16, 0, 0);
    }
    asm volatile("s_waitcnt vmcnt(8)" ::: "memory");   // KT0 landed
    __builtin_amdgcn_sched_barrier(0);
    __builtin_amdgcn_s_barrier();

    // loop-carried G1 frags (a0 k0-half, b0 k0-half) for KT0
    bf16x8 a0[4], b0[4];
    #pragma unroll
    for (int mi = 0; mi < 4; ++mi) a0[mi] = *(const bf16x8*)(aK0 + mi * 1024);
    #pragma unroll
    for (int ni = 0; ni < 4; ++ni) b0[ni] = *(const bf16x8*)(bK0 + ni * 1024);

    // next-to-stage pointers (KT2); bumped +128 elems per 2-KT iteration
    const __bf16* AgN = Ag + 128;
    const __bf16* BgN = Bg + 128;

    // one K-tile body. SO_: this KT's slot elem offset (0|16384); SN_: next
    // KT's slot offset; STG_: 0 none, 1 stage @AgN, 2 stage @AgN+64 (dest =
    // this slot); VM_: 8 / 0 / -1 (vmcnt after M3); LAST_: 1 = no 2nd
    // barrier / no G1 prefetch.
    #define KTBODY(SO_, SN_, STG_, VM_, LAST_)                                 \
    {                                                                          \
        bf16x8 a0h[4], b1[4], a1[4], a1h[4];                                   \
        _Pragma("unroll") for (int mi = 0; mi < 4; ++mi)                       \
            a0h[mi] = *(const bf16x8*)(aK1 + (SO_) + mi * 1024);               \
        _Pragma("unroll") for (int ni = 0; ni < 4; ++ni)                       \
            b1[ni]  = *(const bf16x8*)(bK1 + (SO_) + ni * 1024);               \
        __builtin_amdgcn_s_setprio(1);                                         \
        _Pragma("unroll") for (int mi = 0; mi < 4; ++mi)                       \
            _Pragma("unroll") for (int ni = 0; ni < 4; ++ni)                   \
                acc[mi][ni] = __builtin_amdgcn_mfma_f32_16x16x32_bf16(         \
                    b0[ni], a0[mi], acc[mi][ni], 0, 0, 0);                     \
        __builtin_amdgcn_s_setprio(0);                                         \
        _Pragma("unroll") for (int mi = 0; mi < 4; ++mi) {                     \
            a1[mi]  = *(const bf16x8*)(aK0 + (SO_) + (mi + 4) * 1024);         \
            a1h[mi] = *(const bf16x8*)(aK1 + (SO_) + (mi + 4) * 1024);         \
        }                                                                      \
        __builtin_amdgcn_s_setprio(1);                                         \
        _Pragma("unroll") for (int mi = 0; mi < 4; ++mi)                       \
            _Pragma("unroll") for (int ni = 0; ni < 4; ++ni)                   \
                acc[mi][ni] = __builtin_amdgcn_mfma_f32_16x16x32_bf16(         \
                    b1[ni], a0h[mi], acc[mi][ni], 0, 0, 0);                    \
        __builtin_amdgcn_s_setprio(0);                                         \
        asm volatile("s_waitcnt lgkmcnt(0)" ::: "memory");                     \
        __builtin_amdgcn_sched_barrier(0);                                     \
        __builtin_amdgcn_s_barrier();                                          \
        if (STG_) {                                                            \
            _Pragma("unroll") for (int j = 0; j < 4; ++j)                      \
                __builtin_amdgcn_global_load_lds(                              \
                    (const __attribute__((address_space(1))) void*)(AgN + (long)j * 65536 + ((STG_) == 2 ? 64 : 0)), \
                    (__attribute__((address_space(3))) void*)(&ldsA[(SO_) ? 1 : 0][j * 4096 + ldst]), 16, 0, 0); \
            _Pragma("unroll") for (int j = 0; j < 4; ++j)                      \
                __builtin_amdgcn_global_load_lds(                              \
                    (const __attribute__((address_space(1))) void*)(BgN + (long)j * 65536 + ((STG_) == 2 ? 64 : 0)), \
                    (__attribute__((address_space(3))) void*)(&ldsB[(SO_) ? 1 : 0][j * 4096 + ldst]), 16, 0, 0); \
        }                                                                      \
        __builtin_amdgcn_s_setprio(1);                                         \
        _Pragma("unroll") for (int mi = 0; mi < 4; ++mi)                       \
            _Pragma("unroll") for (int ni = 0; ni < 4; ++ni)                   \
                acc[mi + 4][ni] = __builtin_amdgcn_mfma_f32_16x16x32_bf16(     \
                    b0[ni], a1[mi], acc[mi + 4][ni], 0, 0, 0);                 \
        __builtin_amdgcn_s_setprio(0);                                         \
        if ((VM_) == 8) { asm volatile("s_waitcnt vmcnt(8)" ::: "memory"); }   \
        else if ((VM_) == 0) { asm volatile("s_waitcnt vmcnt(0)" ::: "memory"); } \
        __builtin_amdgcn_sched_barrier(0);                                     \
        if (!(LAST_)) {                                                        \
            __builtin_amdgcn_s_barrier();                                      \
            _Pragma("unroll") for (int mi = 0; mi < 4; ++mi)                   \
                a0[mi] = *(const bf16x8*)(aK0 + (SN_) + mi * 1024);            \
            _Pragma("unroll") for (int ni = 0; ni < 4; ++ni)                   \
                b0[ni] = *(const bf16x8*)(bK0 + (SN_) + ni * 1024);            \
        }                                                                      \
        __builtin_amdgcn_s_setprio(1);                                         \
        _Pragma("unroll") for (int mi = 0; mi < 4; ++mi)                       \
            _Pragma("unroll") for (int ni = 0; ni < 4; ++ni)                   \
                acc[mi + 4][ni] = __builtin_amdgcn_mfma_f32_16x16x32_bf16(     \
                    b1[ni], a1h[mi], acc[mi + 4][ni], 0, 0, 0);                \
        __builtin_amdgcn_s_setprio(0);                                         \
    }

    #pragma unroll 1
    for (int ii = 0; ii < 7; ++ii) {
        KTBODY(0,     16384, 1, 8, 0);   // kt=2ii:   stage kt+2 -> slot0
        KTBODY(16384, 0,     2, 8, 0);   // kt=2ii+1: stage kt+2 -> slot1
        AgN += 128; BgN += 128;
    }
    KTBODY(0,     16384, 0, 0, 0);       // kt=14: drain, prefetch KT15
    KTBODY(16384, 0,     0, -1, 1);      // kt=15: final
    #undef KTBODY

    // ------------------ epilogue ------------------
    // Transposed D: element (row = wm*128+mi*16+fr, col = wn*64+ni*16+g4*4+j).
    // One bf16x4 store per (mi,ni). Lane-local mean partial over b = fr+16*(mi&1).
    const int g4 = lane >> 4;
    const long colb = col0 + wn * 64 + g4 * 4;

    float4 bias4[4];
    #pragma unroll
    for (int ni = 0; ni < 4; ++ni)
        bias4[ni] = *(const float4*)(bias + colb + ni * 16);

    f32x4 msum[2][4];
    #pragma unroll
    for (int bh = 0; bh < 2; ++bh)
        #pragma unroll
        for (int ni = 0; ni < 4; ++ni)
            msum[bh][ni] = f32x4{0.f, 0.f, 0.f, 0.f};

    #pragma unroll
    for (int mi = 0; mi < 8; ++mi) {
        const long row = row0 + wm * 128 + mi * 16 + fr;
        #pragma unroll
        for (int ni = 0; ni < 4; ++ni) {
            f32x4 xv;
            xv[0] = acc[mi][ni][0] + bias4[ni].x;
            xv[1] = acc[mi][ni][1] + bias4[ni].y;
            xv[2] = acc[mi][ni][2] + bias4[ni].z;
            xv[3] = acc[mi][ni][3] + bias4[ni].w;
            bf16x4 xb;
            xb[0] = (__bf16)xv[0]; xb[1] = (__bf16)xv[1];
            xb[2] = (__bf16)xv[2]; xb[3] = (__bf16)xv[3];
            *(bf16x4*)(X + row * 1024 + colb + ni * 16) = xb;
            msum[mi & 1][ni] += xv;
        }
    }

    // cross-wave (wm) reduce of mean partials through LDS (free after K-loop)
    float* ldsf = (float*)&ldsA[0][0];    // 32 b x 256 n f32 = 32 KB
    __syncthreads();                      // all K-loop LDS traffic done
    if (wm == 1) {
        #pragma unroll
        for (int bh = 0; bh < 2; ++bh)
            #pragma unroll
            for (int ni = 0; ni < 4; ++ni)
                *(f32x4*)(ldsf + (bh * 16 + fr) * 256 + wn * 64 + ni * 16 + g4 * 4) = msum[bh][ni];
    }
    __syncthreads();
    if (wm == 0) {
        #pragma unroll
        for (int bh = 0; bh < 2; ++bh) {
            const int b = bh * 16 + fr;
            #pragma unroll
            for (int ni = 0; ni < 4; ++ni) {
                f32x4 other = *(const f32x4*)(ldsf + b * 256 + wn * 64 + ni * 16 + g4 * 4);
                f32x4 tot = msum[bh][ni] + other;
                *(f32x4*)(mpart + ((long)bm * 32 + b) * 1024 + colb + ni * 16) = tot;
            }
        }
    }
}

// ---------------------------------------------------------------------------
// K3: finalize mean from fused partials, gate2[b,h,q] = tanh(m.Wm[q]+bWm[q]).
// ---------------------------------------------------------------------------
__global__ __launch_bounds__(256)
void gate2_k(const float* __restrict__ mpart, const float* __restrict__ Wm,
             const float* __restrict__ bWm, float* __restrict__ g2)
{
    __shared__ float mrow[1024];
    const int b = blockIdx.x;
    const int j4 = threadIdx.x * 4;
    f32x4 s = f32x4{0.f, 0.f, 0.f, 0.f};
    for (int bm = 0; bm < 256; ++bm)
        s += *(const f32x4*)(mpart + ((long)bm * 32 + b) * 1024 + j4);
    mrow[j4 + 0] = s[0] * (1.0f / 2048.0f);
    mrow[j4 + 1] = s[1] * (1.0f / 2048.0f);
    mrow[j4 + 2] = s[2] * (1.0f / 2048.0f);
    mrow[j4 + 3] = s[3] * (1.0f / 2048.0f);
    __syncthreads();
    if (threadIdx.x < 128) {
        const int h = threadIdx.x >> 4;
        const int q = threadIdx.x & 15;
        float d = bWm[q];
        #pragma unroll 8
        for (int k = 0; k < 128; ++k) d += mrow[h * 128 + k] * Wm[q * 128 + k];
        g2[(b * 8 + h) * 16 + q] = tanhf(d);
    }
}

// ---------------------------------------------------------------------------
// K4: scores. X viewed as (524288 rows = bt*8+h, 128). One wave = 16 rows.
// ---------------------------------------------------------------------------
__global__ __launch_bounds__(256)
void scores_k(const __bf16* __restrict__ X, const float* __restrict__ W,
              const float* __restrict__ bW, const float* __restrict__ g2,
              const float* __restrict__ Wh, const float* __restrict__ bWh,
              float* __restrict__ sbuf)
{
    const int tid   = threadIdx.x;
    const int lane  = tid & 63;
    const int w     = tid >> 6;
    const int gw    = blockIdx.x * 4 + w;
    const int rbase = gw * 16;
    const int q     = lane & 15;
    const int g4    = lane >> 4;

    bf16x8 bfr[4];
    #pragma unroll
    for (int c = 0; c < 4; ++c) {
        const float* wp = W + q * 128 + c * 32 + g4 * 8;
        float4 w0 = *(const float4*)wp;
        float4 w1 = *(const float4*)(wp + 4);
        bfr[c] = cvt8(w0, w1);
    }
    const __bf16* xp = X + (long)(rbase + q) * 128 + g4 * 8;
    bf16x8 afr[4];
    #pragma unroll
    for (int c = 0; c < 4; ++c) afr[c] = *(const bf16x8*)(xp + c * 32);

    f32x4 acc = f32x4{0.f, 0.f, 0.f, 0.f};
    #pragma unroll
    for (int c = 0; c < 4; ++c)
        acc = __builtin_amdgcn_mfma_f32_16x16x32_bf16(afr[c], bfr[c], acc, 0, 0, 0);

    const float whq  = Wh[q];
    const float bWv  = bW[q];
    const float bWhv = *bWh;
    #pragma unroll
    for (int r = 0; r < 4; ++r) {
        const int row = rbase + g4 * 4 + r;
        const int h   = row & 7;
        const int bt  = row >> 3;
        const int b   = bt & 31;
        const int t   = bt >> 5;
        float val = tanhf(acc[r] + bWv) * g2[(b * 8 + h) * 16 + q] * whq;
        val += __shfl_xor(val, 1);
        val += __shfl_xor(val, 2);
        val += __shfl_xor(val, 4);
        val += __shfl_xor(val, 8);
        if (q == 0) sbuf[(b * 8 + h) * 2048 + t] = val + bWhv;
    }
}

// ---------------------------------------------------------------------------
// K5: softmax over t, in place. 256 blocks (b*8+h).
// ---------------------------------------------------------------------------
__global__ __launch_bounds__(256)
void softmax_k(float* __restrict__ s)
{
    __shared__ float red[256];
    const int bh = blockIdx.x;
    const int tid = threadIdx.x;
    float* row = s + bh * 2048;
    float4 v0 = *(const float4*)(row + tid * 8);
    float4 v1 = *(const float4*)(row + tid * 8 + 4);
    float v[8] = {v0.x, v0.y, v0.z, v0.w, v1.x, v1.y, v1.z, v1.w};
    float mx = v[0];
    #pragma unroll
    for (int i = 1; i < 8; ++i) mx = fmaxf(mx, v[i]);
    red[tid] = mx;
    __syncthreads();
    for (int st = 128; st > 0; st >>= 1) {
        if (tid < st) red[tid] = fmaxf(red[tid], red[tid + st]);
        __syncthreads();
    }
    mx = red[0];
    __syncthreads();
    float sum = 0.f;
    #pragma unroll
    for (int i = 0; i < 8; ++i) { v[i] = expf(v[i] - mx); sum += v[i]; }
    red[tid] = sum;
    __syncthreads();
    for (int st = 128; st > 0; st >>= 1) {
        if (tid < st) red[tid] += red[tid + st];
        __syncthreads();
    }
    const float inv = 1.0f / red[0];
    *(float4*)(row + tid * 8)     = make_float4(v[0] * inv, v[1] * inv, v[2] * inv, v[3] * inv);
    *(float4*)(row + tid * 8 + 4) = make_float4(v[4] * inv, v[5] * inv, v[6] * inv, v[7] * inv);
}

// ---------------------------------------------------------------------------
// K6: weighted sum over t, t split 8 ways. 2048 blocks.
// ---------------------------------------------------------------------------
__global__ __launch_bounds__(256)
void wsum_k(const float* __restrict__ a, const __bf16* __restrict__ X,
            float* __restrict__ wpart)
{
    __shared__ float pk[8 * 128];
    const int bx = blockIdx.x;
    const int tc = bx & 7;
    const int bh = bx >> 3;
    const int b  = bh >> 3;
    const int h  = bh & 7;
    const int tid = threadIdx.x;
    const int kq = tid & 31;
    const int tr = tid >> 5;
    const float* ar = a + bh * 2048 + tc * 256;
    float a0 = 0.f, a1 = 0.f, a2 = 0.f, a3 = 0.f;
    #pragma unroll 4
    for (int i = tr; i < 256; i += 8) {
        const int t = tc * 256 + i;
        const float av = ar[i];
        bf16x4 xv = *(const bf16x4*)(X + (long)(t * 32 + b) * 1024 + h * 128 + kq * 4);
        a0 += av * (float)xv[0];
        a1 += av * (float)xv[1];
        a2 += av * (float)xv[2];
        a3 += av * (float)xv[3];
    }
    pk[tr * 128 + kq * 4 + 0] = a0;
    pk[tr * 128 + kq * 4 + 1] = a1;
    pk[tr * 128 + kq * 4 + 2] = a2;
    pk[tr * 128 + kq * 4 + 3] = a3;
    __syncthreads();
    if (tid < 128) {
        float s2 = 0.f;
        #pragma unroll
        for (int r = 0; r < 8; ++r) s2 += pk[r * 128 + tid];
        wpart[(long)bx * 128 + tid] = s2;
    }
}

// K7: reduce the 8 t-chunks.
__global__ __launch_bounds__(256)
void wsum_fin(const float* __restrict__ wpart, float* __restrict__ out)
{
    const int idx = blockIdx.x * 256 + threadIdx.x;
    const int k  = idx & 127;
    const int bh = idx >> 7;
    const int b  = bh >> 3;
    const int h  = bh & 7;
    float s = 0.f;
    #pragma unroll
    for (int tc = 0; tc < 8; ++tc) s += wpart[(bh * 8 + tc) * 128 + k];
    out[b * 1024 + h * 128 + k] = s;
}

extern "C" void kernel_launch(void* const* d_in, const int* in_sizes, int n_in,
                              void* d_out, int out_size, void* d_ws, size_t ws_size,
                              hipStream_t stream)
{
    const float* hyp = (const float*)d_in[0];
    const float* Wmh = (const float*)d_in[1];
    const float* bmh = (const float*)d_in[2];
    const float* W   = (const float*)d_in[3];
    const float* bW  = (const float*)d_in[4];
    const float* Wm  = (const float*)d_in[5];
    const float* bWm = (const float*)d_in[6];
    const float* Wh  = (const float*)d_in[7];
    const float* bWh = (const float*)d_in[8];
    float* out = (float*)d_out;

    char* ws = (char*)d_ws;
    const size_t SZ_X   = 134217728;   // X bf16 (65536 x 1024)
    const size_t SZ_AB  = 134217728;   // Ab bf16 hyp
    const size_t SZ_BB  = 2097152;     // Bb bf16 Wmh
    const size_t SZ_MP  = 33554432;    // mpart f32 (256 x 32 x 1024)
    const size_t SZ_G2  = 16384;
    const size_t SZ_SB  = 2097152;

    size_t off = 0;
    __bf16* X     = (__bf16*)(ws + off); off += SZ_X;
    __bf16* Ab    = (__bf16*)(ws + off); off += SZ_AB;
    __bf16* Bb    = (__bf16*)(ws + off); off += SZ_BB;
    float*  mpart = (float*) (ws + off); off += SZ_MP;
    float*  g2    = (float*) (ws + off); off += SZ_G2;
    float*  sbuf  = (float*) (ws + off); off += SZ_SB;
    float*  wpart = (float*) (ws + off);

    cvt_f32_bf16<<<32768, 256, 0, stream>>>(hyp, Ab);
    cvt_f32_bf16<<<512,   256, 0, stream>>>(Wmh, Bb);
    gemm_x_8ph<<<1024, 512, 0, stream>>>(Ab, Bb, bmh, X, mpart);
    gate2_k<<<32, 256, 0, stream>>>(mpart, Wm, bWm, g2);
    scores_k<<<8192, 256, 0, stream>>>(X, W, bW, g2, Wh, bWh, sbuf);
    softmax_k<<<256, 256, 0, stream>>>(sbuf);
    wsum_k<<<2048, 256, 0, stream>>>(sbuf, X, wpart);
    wsum_fin<<<128, 256, 0, stream>>>(wpart, out);
}

// Round 9
// 328.369 us; speedup vs baseline: 1.6262x; 1.0411x over previous
//
#include <hip/hip_runtime.h>
#include <hip/hip_bf16.h>

// Problem constants (T=2048, B=32, N=1024, H=8, K=128, K2=16)
#define T_DIM 2048
#define B_DIM 32
#define N_DIM 1024
#define H_DIM 8
#define K_DIM 128
#define Q_DIM 16

typedef __bf16 bf16x8 __attribute__((ext_vector_type(8)));
typedef __bf16 bf16x4 __attribute__((ext_vector_type(4)));
typedef float  f32x4  __attribute__((ext_vector_type(4)));

__device__ inline bf16x8 cvt8(float4 a, float4 b) {
    bf16x8 r;
    r[0] = (__bf16)a.x; r[1] = (__bf16)a.y; r[2] = (__bf16)a.z; r[3] = (__bf16)a.w;
    r[4] = (__bf16)b.x; r[5] = (__bf16)b.y; r[6] = (__bf16)b.z; r[7] = (__bf16)b.w;
    return r;
}

// ---------------------------------------------------------------------------
// K0: f32 -> bf16 convert, 8 elems/thread.
// ---------------------------------------------------------------------------
__global__ __launch_bounds__(256)
void cvt_f32_bf16(const float* __restrict__ s, __bf16* __restrict__ d)
{
    const long i = ((long)blockIdx.x * 256 + threadIdx.x) * 8;
    float4 a = *(const float4*)(s + i);
    float4 b = *(const float4*)(s + i + 4);
    *(bf16x8*)(d + i) = cvt8(a, b);
}

// ---------------------------------------------------------------------------
// K1: faithful m201 8-phase 256x256 GEMM (plain HIP). Per K-tile, 4 phases:
//   {ds_read subtile (8/8/4/4 b128) | stage 1 half-tile (2 gload_lds) |
//    s_barrier | lgkmcnt(0)+sched_barrier | setprio(1) 16 MFMA setprio(0) |
//    s_barrier}
// Stage schedule (provably race-free):
//   ph1/ph2: KT(i+1).A half0/half1 -> slot s^1 (freed at KT i-1 ph4 barrier)
//   ph3/ph4: KT(i+2).B half0/half1 -> slot s   (B of KT i drained after ph2)
// vmcnt(4) once per KT at ph4 (steady state leaves KT i+2's 4 B-loads in
// flight; never 0 mid-loop). Prologue: KT0 full + KT1.B (12 loads), vmcnt(4).
// Operand-swapped MFMA (transposed D), XOR-swizzled LDS, unroll-by-2 so all
// ds offsets are 16-bit immediates. Fused time-mean partials in epilogue.
// ---------------------------------------------------------------------------
__global__ __launch_bounds__(512, 1)
void gemm_x_8ph(const __bf16* __restrict__ A, const __bf16* __restrict__ Bw,
                const float* __restrict__ bias, __bf16* __restrict__ X,
                float* __restrict__ mpart)
{
    __shared__ __bf16 ldsA[2][16384];   // [slot][256 rows * 64 k]
    __shared__ __bf16 ldsB[2][16384];
    __bf16* ldsAf = &ldsA[0][0];
    __bf16* ldsBf = &ldsB[0][0];

    const int tid  = threadIdx.x;
    const int lane = tid & 63;
    const int w    = tid >> 6;     // 0..7
    const int wm   = w >> 2;       // 0..1 -> 128 rows
    const int wn   = w & 3;        // 0..3 -> 64 cols

    const int bid  = blockIdx.x;                    // 1024 blocks, %8==0
    const int wgid = (bid & 7) * 128 + (bid >> 3);  // bijective XCD swizzle
    const int bm   = wgid >> 2;                     // 0..255
    const int bn   = wgid & 3;                      // 0..3
    const long row0 = (long)bm * 256;
    const long col0 = (long)bn * 256;

    // staging: one half-tile (128 rows) = 2 gloads; thread covers row
    // j*64 + w*8 + (lane>>3) within the half. Global col chunk pre-swizzled.
    const int srow = w * 8 + (lane >> 3);
    const int scol = ((lane & 7) ^ (lane >> 3)) * 8;
    const __bf16* Ag = A  + (row0 + srow) * 1024 + scol;
    const __bf16* Bg = Bw + (col0 + srow) * 1024 + scol;
    const int ldst = w * 512;   // LDS dest elem base, wave-uniform

    const int fr = lane & 15;
    const int g2 = lane >> 4;    // 0..3: 16B chunk within k-half
    const int x7 = lane & 7;     // read-side XOR key

    // per-thread LDS read bases; reads = base + compile-time immediate.
    const __bf16* aK0 = ldsAf + (wm * 128 + fr) * 64 + ((g2    ) ^ x7) * 8;
    const __bf16* aK1 = ldsAf + (wm * 128 + fr) * 64 + ((4 + g2) ^ x7) * 8;
    const __bf16* bK0 = ldsBf + (wn * 64  + fr) * 64 + ((g2    ) ^ x7) * 8;
    const __bf16* bK1 = ldsBf + (wn * 64  + fr) * 64 + ((4 + g2) ^ x7) * 8;

    f32x4 acc[8][4];
    #pragma unroll
    for (int i = 0; i < 8; ++i)
        #pragma unroll
        for (int j = 0; j < 4; ++j)
            acc[i][j] = f32x4{0.f, 0.f, 0.f, 0.f};

    #define GLDA(SRC_, DST_) __builtin_amdgcn_global_load_lds( \
        (const __attribute__((address_space(1))) void*)(SRC_), \
        (__attribute__((address_space(3))) void*)(DST_), 16, 0, 0)

    // ---- prologue: KT0.{A0,A1,B0,B1}, KT1.{B0,B1} = 12 loads (issue order!)
    #pragma unroll
    for (int j = 0; j < 2; ++j) GLDA(Ag + (long)j * 65536,          ldsAf + j * 4096 + ldst);
    #pragma unroll
    for (int j = 0; j < 2; ++j) GLDA(Ag + 131072 + (long)j * 65536, ldsAf + 8192 + j * 4096 + ldst);
    #pragma unroll
    for (int j = 0; j < 2; ++j) GLDA(Bg + (long)j * 65536,          ldsBf + j * 4096 + ldst);
    #pragma unroll
    for (int j = 0; j < 2; ++j) GLDA(Bg + 131072 + (long)j * 65536, ldsBf + 8192 + j * 4096 + ldst);
    #pragma unroll
    for (int j = 0; j < 2; ++j) GLDA(Bg + 64 + (long)j * 65536,          ldsBf + 16384 + j * 4096 + ldst);
    #pragma unroll
    for (int j = 0; j < 2; ++j) GLDA(Bg + 64 + 131072 + (long)j * 65536, ldsBf + 16384 + 8192 + j * 4096 + ldst);
    asm volatile("s_waitcnt vmcnt(4)" ::: "memory");   // KT0 landed; KT1.B in flight
    __builtin_amdgcn_sched_barrier(0);
    __builtin_amdgcn_s_barrier();

    // stage source pointers: AgN -> KT(i+1).A base; BgN -> KT(i+2).B base
    const __bf16* AgN = Ag + 64;
    const __bf16* BgN = Bg + 128;

    #define MFMA16(AF_, BF_, OFF_)                                             \
        __builtin_amdgcn_s_setprio(1);                                         \
        _Pragma("unroll") for (int mi = 0; mi < 4; ++mi)                       \
            _Pragma("unroll") for (int ni = 0; ni < 4; ++ni)                   \
                acc[mi + (OFF_)][ni] = __builtin_amdgcn_mfma_f32_16x16x32_bf16(\
                    BF_[ni], AF_[mi], acc[mi + (OFF_)][ni], 0, 0, 0);          \
        __builtin_amdgcn_s_setprio(0);

    #define LGKM0()                                                            \
        asm volatile("s_waitcnt lgkmcnt(0)" ::: "memory");                     \
        __builtin_amdgcn_sched_barrier(0);

    // One K-tile = 4 template phases. SO_: this KT's slot offset; SN_: other.
    // KO_: 0|64 (k-offset of stage sources within the pair). STGA_/STGB_ gate
    // the A(i+1)/B(i+2) stages. VM_: 4 -> vmcnt(4), 0 -> vmcnt(0), -1 none.
    #define KTBODY(SO_, SN_, KO_, STGA_, STGB_, VM_)                           \
    {                                                                          \
        bf16x8 a0[4], b0[4], a0h[4], b1[4], a1[4], a1h[4];                     \
        /* ---- ph1: read a0(k0) x4 + b0(k0) x4; stage KT(i+1).A0 */           \
        _Pragma("unroll") for (int mi = 0; mi < 4; ++mi)                       \
            a0[mi] = *(const bf16x8*)(aK0 + (SO_) + mi * 1024);                \
        _Pragma("unroll") for (int ni = 0; ni < 4; ++ni)                       \
            b0[ni] = *(const bf16x8*)(bK0 + (SO_) + ni * 1024);                \
        if (STGA_) {                                                           \
            _Pragma("unroll") for (int j = 0; j < 2; ++j)                      \
                GLDA(AgN + (KO_) + (long)j * 65536,                            \
                     ldsAf + (SN_) + j * 4096 + ldst);                         \
        }                                                                      \
        __builtin_amdgcn_s_barrier();                                          \
        LGKM0();                                                               \
        MFMA16(a0, b0, 0);                                                     \
        __builtin_amdgcn_s_barrier();                                          \
        /* ---- ph2: read a0h(k1) x4 + b1(k1) x4; stage KT(i+1).A1 */          \
        _Pragma("unroll") for (int mi = 0; mi < 4; ++mi)                       \
            a0h[mi] = *(const bf16x8*)(aK1 + (SO_) + mi * 1024);               \
        _Pragma("unroll") for (int ni = 0; ni < 4; ++ni)                       \
            b1[ni]  = *(const bf16x8*)(bK1 + (SO_) + ni * 1024);               \
        if (STGA_) {                                                           \
            _Pragma("unroll") for (int j = 0; j < 2; ++j)                      \
                GLDA(AgN + (KO_) + 131072 + (long)j * 65536,                   \
                     ldsAf + (SN_) + 8192 + j * 4096 + ldst);                  \
        }                                                                      \
        __builtin_amdgcn_s_barrier();                                          \
        LGKM0();                                                               \
        MFMA16(a0h, b1, 0);                                                    \
        __builtin_amdgcn_s_barrier();                                          \
        /* ---- ph3: read a1(k0) x4; stage KT(i+2).B0 -> slot SO */            \
        _Pragma("unroll") for (int mi = 0; mi < 4; ++mi)                       \
            a1[mi] = *(const bf16x8*)(aK0 + (SO_) + (mi + 4) * 1024);          \
        if (STGB_) {                                                           \
            _Pragma("unroll") for (int j = 0; j < 2; ++j)                      \
                GLDA(BgN + (KO_) + (long)j * 65536,                            \
                     ldsBf + (SO_) + j * 4096 + ldst);                         \
        }                                                                      \
        __builtin_amdgcn_s_barrier();                                          \
        LGKM0();                                                               \
        MFMA16(a1, b0, 4);                                                     \
        __builtin_amdgcn_s_barrier();                                          \
        /* ---- ph4: read a1h(k1) x4; stage KT(i+2).B1; vmcnt; MFMA */         \
        _Pragma("unroll") for (int mi = 0; mi < 4; ++mi)                       \
            a1h[mi] = *(const bf16x8*)(aK1 + (SO_) + (mi + 4) * 1024);         \
        if (STGB_) {                                                           \
            _Pragma("unroll") for (int j = 0; j < 2; ++j)                      \
                GLDA(BgN + (KO_) + 131072 + (long)j * 65536,                   \
                     ldsBf + (SO_) + 8192 + j * 4096 + ldst);                  \
        }                                                                      \
        if ((VM_) == 4)      { asm volatile("s_waitcnt vmcnt(4)" ::: "memory"); } \
        else if ((VM_) == 0) { asm volatile("s_waitcnt vmcnt(0)" ::: "memory"); } \
        __builtin_amdgcn_sched_barrier(0);                                     \
        __builtin_amdgcn_s_barrier();                                          \
        LGKM0();                                                               \
        MFMA16(a1h, b1, 4);                                                    \
        __builtin_amdgcn_s_barrier();                                          \
    }

    #pragma unroll 1
    for (int ii = 0; ii < 7; ++ii) {       // KT 0..13
        KTBODY(0,     16384, 0,  1, 1, 4);
        KTBODY(16384, 0,     64, 1, 1, 4);
        AgN += 128; BgN += 128;
    }
    KTBODY(0,     16384, 0, 1, 0, 0);      // KT14: stage KT15.A, drain
    KTBODY(16384, 0,     0, 0, 0, -1);     // KT15: final
    #undef KTBODY
    #undef MFMA16
    #undef LGKM0
    #undef GLDA

    // ------------------ epilogue ------------------
    // Transposed D: element (row = wm*128+mi*16+fr, col = wn*64+ni*16+g4*4+j).
    // One bf16x4 store per (mi,ni). Lane-local mean partial over b = fr+16*(mi&1).
    const int g4 = lane >> 4;
    const long colb = col0 + wn * 64 + g4 * 4;

    float4 bias4[4];
    #pragma unroll
    for (int ni = 0; ni < 4; ++ni)
        bias4[ni] = *(const float4*)(bias + colb + ni * 16);

    f32x4 msum[2][4];
    #pragma unroll
    for (int bh = 0; bh < 2; ++bh)
        #pragma unroll
        for (int ni = 0; ni < 4; ++ni)
            msum[bh][ni] = f32x4{0.f, 0.f, 0.f, 0.f};

    #pragma unroll
    for (int mi = 0; mi < 8; ++mi) {
        const long row = row0 + wm * 128 + mi * 16 + fr;
        #pragma unroll
        for (int ni = 0; ni < 4; ++ni) {
            f32x4 xv;
            xv[0] = acc[mi][ni][0] + bias4[ni].x;
            xv[1] = acc[mi][ni][1] + bias4[ni].y;
            xv[2] = acc[mi][ni][2] + bias4[ni].z;
            xv[3] = acc[mi][ni][3] + bias4[ni].w;
            bf16x4 xb;
            xb[0] = (__bf16)xv[0]; xb[1] = (__bf16)xv[1];
            xb[2] = (__bf16)xv[2]; xb[3] = (__bf16)xv[3];
            *(bf16x4*)(X + row * 1024 + colb + ni * 16) = xb;
            msum[mi & 1][ni] += xv;
        }
    }

    // cross-wave (wm) reduce of mean partials through LDS (free after K-loop)
    float* ldsf = (float*)ldsAf;          // 32 b x 256 n f32 = 32 KB
    __syncthreads();                      // all K-loop LDS traffic done
    if (wm == 1) {
        #pragma unroll
        for (int bh = 0; bh < 2; ++bh)
            #pragma unroll
            for (int ni = 0; ni < 4; ++ni)
                *(f32x4*)(ldsf + (bh * 16 + fr) * 256 + wn * 64 + ni * 16 + g4 * 4) = msum[bh][ni];
    }
    __syncthreads();
    if (wm == 0) {
        #pragma unroll
        for (int bh = 0; bh < 2; ++bh) {
            const int b = bh * 16 + fr;
            #pragma unroll
            for (int ni = 0; ni < 4; ++ni) {
                f32x4 other = *(const f32x4*)(ldsf + b * 256 + wn * 64 + ni * 16 + g4 * 4);
                f32x4 tot = msum[bh][ni] + other;
                *(f32x4*)(mpart + ((long)bm * 32 + b) * 1024 + colb + ni * 16) = tot;
            }
        }
    }
}

// ---------------------------------------------------------------------------
// K3: finalize mean from fused partials, gate2[b,h,q] = tanh(m.Wm[q]+bWm[q]).
// ---------------------------------------------------------------------------
__global__ __launch_bounds__(256)
void gate2_k(const float* __restrict__ mpart, const float* __restrict__ Wm,
             const float* __restrict__ bWm, float* __restrict__ g2)
{
    __shared__ float mrow[1024];
    const int b = blockIdx.x;
    const int j4 = threadIdx.x * 4;
    f32x4 s = f32x4{0.f, 0.f, 0.f, 0.f};
    for (int bm = 0; bm < 256; ++bm)
        s += *(const f32x4*)(mpart + ((long)bm * 32 + b) * 1024 + j4);
    mrow[j4 + 0] = s[0] * (1.0f / 2048.0f);
    mrow[j4 + 1] = s[1] * (1.0f / 2048.0f);
    mrow[j4 + 2] = s[2] * (1.0f / 2048.0f);
    mrow[j4 + 3] = s[3] * (1.0f / 2048.0f);
    __syncthreads();
    if (threadIdx.x < 128) {
        const int h = threadIdx.x >> 4;
        const int q = threadIdx.x & 15;
        float d = bWm[q];
        #pragma unroll 8
        for (int k = 0; k < 128; ++k) d += mrow[h * 128 + k] * Wm[q * 128 + k];
        g2[(b * 8 + h) * 16 + q] = tanhf(d);
    }
}

// ---------------------------------------------------------------------------
// K4: scores. X viewed as (524288 rows = bt*8+h, 128). One wave = 16 rows.
// ---------------------------------------------------------------------------
__global__ __launch_bounds__(256)
void scores_k(const __bf16* __restrict__ X, const float* __restrict__ W,
              const float* __restrict__ bW, const float* __restrict__ g2,
              const float* __restrict__ Wh, const float* __restrict__ bWh,
              float* __restrict__ sbuf)
{
    const int tid   = threadIdx.x;
    const int lane  = tid & 63;
    const int w     = tid >> 6;
    const int gw    = blockIdx.x * 4 + w;
    const int rbase = gw * 16;
    const int q     = lane & 15;
    const int g4    = lane >> 4;

    bf16x8 bfr[4];
    #pragma unroll
    for (int c = 0; c < 4; ++c) {
        const float* wp = W + q * 128 + c * 32 + g4 * 8;
        float4 w0 = *(const float4*)wp;
        float4 w1 = *(const float4*)(wp + 4);
        bfr[c] = cvt8(w0, w1);
    }
    const __bf16* xp = X + (long)(rbase + q) * 128 + g4 * 8;
    bf16x8 afr[4];
    #pragma unroll
    for (int c = 0; c < 4; ++c) afr[c] = *(const bf16x8*)(xp + c * 32);

    f32x4 acc = f32x4{0.f, 0.f, 0.f, 0.f};
    #pragma unroll
    for (int c = 0; c < 4; ++c)
        acc = __builtin_amdgcn_mfma_f32_16x16x32_bf16(afr[c], bfr[c], acc, 0, 0, 0);

    const float whq  = Wh[q];
    const float bWv  = bW[q];
    const float bWhv = *bWh;
    #pragma unroll
    for (int r = 0; r < 4; ++r) {
        const int row = rbase + g4 * 4 + r;
        const int h   = row & 7;
        const int bt  = row >> 3;
        const int b   = bt & 31;
        const int t   = bt >> 5;
        float val = tanhf(acc[r] + bWv) * g2[(b * 8 + h) * 16 + q] * whq;
        val += __shfl_xor(val, 1);
        val += __shfl_xor(val, 2);
        val += __shfl_xor(val, 4);
        val += __shfl_xor(val, 8);
        if (q == 0) sbuf[(b * 8 + h) * 2048 + t] = val + bWhv;
    }
}

// ---------------------------------------------------------------------------
// K5: softmax over t, in place. 256 blocks (b*8+h).
// ---------------------------------------------------------------------------
__global__ __launch_bounds__(256)
void softmax_k(float* __restrict__ s)
{
    __shared__ float red[256];
    const int bh = blockIdx.x;
    const int tid = threadIdx.x;
    float* row = s + bh * 2048;
    float4 v0 = *(const float4*)(row + tid * 8);
    float4 v1 = *(const float4*)(row + tid * 8 + 4);
    float v[8] = {v0.x, v0.y, v0.z, v0.w, v1.x, v1.y, v1.z, v1.w};
    float mx = v[0];
    #pragma unroll
    for (int i = 1; i < 8; ++i) mx = fmaxf(mx, v[i]);
    red[tid] = mx;
    __syncthreads();
    for (int st = 128; st > 0; st >>= 1) {
        if (tid < st) red[tid] = fmaxf(red[tid], red[tid + st]);
        __syncthreads();
    }
    mx = red[0];
    __syncthreads();
    float sum = 0.f;
    #pragma unroll
    for (int i = 0; i < 8; ++i) { v[i] = expf(v[i] - mx); sum += v[i]; }
    red[tid] = sum;
    __syncthreads();
    for (int st = 128; st > 0; st >>= 1) {
        if (tid < st) red[tid] += red[tid + st];
        __syncthreads();
    }
    const float inv = 1.0f / red[0];
    *(float4*)(row + tid * 8)     = make_float4(v[0] * inv, v[1] * inv, v[2] * inv, v[3] * inv);
    *(float4*)(row + tid * 8 + 4) = make_float4(v[4] * inv, v[5] * inv, v[6] * inv, v[7] * inv);
}

// ---------------------------------------------------------------------------
// K6: weighted sum over t, t split 8 ways. 2048 blocks.
// ---------------------------------------------------------------------------
__global__ __launch_bounds__(256)
void wsum_k(const float* __restrict__ a, const __bf16* __restrict__ X,
            float* __restrict__ wpart)
{
    __shared__ float pk[8 * 128];
    const int bx = blockIdx.x;
    const int tc = bx & 7;
    const int bh = bx >> 3;
    const int b  = bh >> 3;
    const int h  = bh & 7;
    const int tid = threadIdx.x;
    const int kq = tid & 31;
    const int tr = tid >> 5;
    const float* ar = a + bh * 2048 + tc * 256;
    float a0 = 0.f, a1 = 0.f, a2 = 0.f, a3 = 0.f;
    #pragma unroll 4
    for (int i = tr; i < 256; i += 8) {
        const int t = tc * 256 + i;
        const float av = ar[i];
        bf16x4 xv = *(const bf16x4*)(X + (long)(t * 32 + b) * 1024 + h * 128 + kq * 4);
        a0 += av * (float)xv[0];
        a1 += av * (float)xv[1];
        a2 += av * (float)xv[2];
        a3 += av * (float)xv[3];
    }
    pk[tr * 128 + kq * 4 + 0] = a0;
    pk[tr * 128 + kq * 4 + 1] = a1;
    pk[tr * 128 + kq * 4 + 2] = a2;
    pk[tr * 128 + kq * 4 + 3] = a3;
    __syncthreads();
    if (tid < 128) {
        float s2 = 0.f;
        #pragma unroll
        for (int r = 0; r < 8; ++r) s2 += pk[r * 128 + tid];
        wpart[(long)bx * 128 + tid] = s2;
    }
}

// K7: reduce the 8 t-chunks.
__global__ __launch_bounds__(256)
void wsum_fin(const float* __restrict__ wpart, float* __restrict__ out)
{
    const int idx = blockIdx.x * 256 + threadIdx.x;
    const int k  = idx & 127;
    const int bh = idx >> 7;
    const int b  = bh >> 3;
    const int h  = bh & 7;
    float s = 0.f;
    #pragma unroll
    for (int tc = 0; tc < 8; ++tc) s += wpart[(bh * 8 + tc) * 128 + k];
    out[b * 1024 + h * 128 + k] = s;
}

extern "C" void kernel_launch(void* const* d_in, const int* in_sizes, int n_in,
                              void* d_out, int out_size, void* d_ws, size_t ws_size,
                              hipStream_t stream)
{
    const float* hyp = (const float*)d_in[0];
    const float* Wmh = (const float*)d_in[1];
    const float* bmh = (const float*)d_in[2];
    const float* W   = (const float*)d_in[3];
    const float* bW  = (const float*)d_in[4];
    const float* Wm  = (const float*)d_in[5];
    const float* bWm = (const float*)d_in[6];
    const float* Wh  = (const float*)d_in[7];
    const float* bWh = (const float*)d_in[8];
    float* out = (float*)d_out;

    char* ws = (char*)d_ws;
    const size_t SZ_X   = 134217728;   // X bf16 (65536 x 1024)
    const size_t SZ_AB  = 134217728;   // Ab bf16 hyp
    const size_t SZ_BB  = 2097152;     // Bb bf16 Wmh
    const size_t SZ_MP  = 33554432;    // mpart f32 (256 x 32 x 1024)
    const size_t SZ_G2  = 16384;
    const size_t SZ_SB  = 2097152;

    size_t off = 0;
    __bf16* X     = (__bf16*)(ws + off); off += SZ_X;
    __bf16* Ab    = (__bf16*)(ws + off); off += SZ_AB;
    __bf16* Bb    = (__bf16*)(ws + off); off += SZ_BB;
    float*  mpart = (float*) (ws + off); off += SZ_MP;
    float*  g2    = (float*) (ws + off); off += SZ_G2;
    float*  sbuf  = (float*) (ws + off); off += SZ_SB;
    float*  wpart = (float*) (ws + off);

    cvt_f32_bf16<<<32768, 256, 0, stream>>>(hyp, Ab);
    cvt_f32_bf16<<<512,   256, 0, stream>>>(Wmh, Bb);
    gemm_x_8ph<<<1024, 512, 0, stream>>>(Ab, Bb, bmh, X, mpart);
    gate2_k<<<32, 256, 0, stream>>>(mpart, Wm, bWm, g2);
    scores_k<<<8192, 256, 0, stream>>>(X, W, bW, g2, Wh, bWh, sbuf);
    softmax_k<<<256, 256, 0, stream>>>(sbuf);
    wsum_k<<<2048, 256, 0, stream>>>(sbuf, X, wpart);
    wsum_fin<<<128, 256, 0, stream>>>(wpart, out);
}